// Round 13
// baseline (142.009 us; speedup 1.0000x reference)
//
#include <hip/hip_runtime.h>

#define BSALL     64
#define W_TOTAL_C 2234368
#define B_TOTAL_C 3526

__device__ __forceinline__ float silu_f(float v) {
    return v / (1.f + __expf(-v));
}

// ---------------------------------------------------------------------------
// Layer params. SB = sample base (0 or 32); each instance covers 32 samples.
// NBLK = GX*NKY*32 blocks of 128 threads.
template<int DIN_, int DOUT_, int KC_, int NKY_, int GX_, int PNK_, int VEC_,
         bool FINAL_, int WOFF_, int PBOFF_, int FBOFF_, int SB_>
struct LP {
    static constexpr int  DIN = DIN_, DOUT = DOUT_, KC = KC_, NKY = NKY_,
                          GX = GX_, PNK = PNK_, VEC = VEC_, WOFF = WOFF_,
                          PBOFF = PBOFF_, FBOFF = FBOFF_, SB = SB_;
    static constexpr bool FINAL = FINAL_;
    static constexpr int  NBLK = GX_ * NKY_ * 32;
};

// Champion layer body (R11), refactored: flat bid decode, 128-thread blocks.
template<class P>
__device__ __forceinline__
void layer_body(int bid, int tid,
                const float* __restrict__ hin,   // x or prev partials
                float* __restrict__ outp,        // partials slice, or d_out
                const float* __restrict__ wbase,
                const float* __restrict__ bias,
                float* sh)
{
    const int b    = P::SB + (bid & 31);
    const int rest = bid >> 5;
    const int ky   = rest % P::NKY;
    const int gx   = rest / P::NKY;
    const int k0   = ky * P::KC;

    // ---- stage h chunk (fused prev-layer reduce + bias + silu) ----
    for (int i = tid; i < P::KC; i += 128) {
        float s;
        if (P::PNK == 0) {
            s = hin[b * P::DIN + k0 + i];
        } else {
            s = bias[b * B_TOTAL_C + P::PBOFF + k0 + i];
            #pragma unroll
            for (int k = 0; k < P::PNK; ++k)
                s += hin[((size_t)k * BSALL + b) * P::DIN + k0 + i];
            s = silu_f(s);
        }
        sh[i] = s;
    }
    __syncthreads();

    const int o = (gx * 128 + tid) * P::VEC;
    if (o >= P::DOUT) return;

    float a0 = 0.f, a1 = 0.f, a2 = 0.f, a3 = 0.f;
    const float* wp = wbase + (size_t)b * W_TOTAL_C + P::WOFF
                            + (size_t)k0 * P::DOUT + o;
    if (P::VEC == 4) {
        #pragma unroll 16
        for (int i = 0; i < P::KC; ++i) {
            const float hv = sh[i];
            const float4 w = *reinterpret_cast<const float4*>(wp);
            a0 = fmaf(hv, w.x, a0);
            a1 = fmaf(hv, w.y, a1);
            a2 = fmaf(hv, w.z, a2);
            a3 = fmaf(hv, w.w, a3);
            wp += P::DOUT;
        }
    } else {
        #pragma unroll 16
        for (int i = 0; i < P::KC; ++i) {
            const float hv = sh[i];
            const float2 w = *reinterpret_cast<const float2*>(wp);
            a0 = fmaf(hv, w.x, a0);
            a1 = fmaf(hv, w.y, a1);
            wp += P::DOUT;
        }
    }

    if (P::FINAL) {
        float v0 = a0 + bias[b * B_TOTAL_C + P::FBOFF + o];
        outp[b * P::DOUT + o] = tanhf(v0);
        if (o + 1 < P::DOUT) {
            float v1 = a1 + bias[b * B_TOTAL_C + P::FBOFF + o + 1];
            outp[b * P::DOUT + o + 1] = tanhf(v1);
        }
    } else {
        float* pp = outp + ((size_t)ky * BSALL + b) * P::DOUT + o;
        if (P::VEC == 4) *reinterpret_cast<float4*>(pp) = make_float4(a0, a1, a2, a3);
        else { pp[0] = a0; pp[1] = a1; }
    }
}

// one layer-group per dispatch
template<class A>
__global__ __launch_bounds__(128)
void mono_kernel(const float* __restrict__ hinA, float* __restrict__ outA,
                 const float* __restrict__ wts, const float* __restrict__ bias)
{
    __shared__ float sh[512];
    layer_body<A>(blockIdx.x, threadIdx.x, hinA, outA, wts, bias, sh);
}

// two INDEPENDENT layer-groups fused into one dispatch (pipeline overlap):
// blocks [0, A::NBLK) do A; blocks [A::NBLK, A::NBLK+B::NBLK) do B.
template<class A, class B>
__global__ __launch_bounds__(128)
void dual_kernel(const float* __restrict__ hinA, float* __restrict__ outA,
                 const float* __restrict__ hinB, float* __restrict__ outB,
                 const float* __restrict__ wts, const float* __restrict__ bias)
{
    __shared__ float sh[512];
    const int bid = blockIdx.x;
    if (bid < A::NBLK)
        layer_body<A>(bid, threadIdx.x, hinA, outA, wts, bias, sh);
    else
        layer_body<B>(bid - A::NBLK, threadIdx.x, hinB, outB, wts, bias, sh);
}

// ---------------------------------------------------------------------------
// Layer configs (two sample-groups: A = samples 0-31, B = 32-63)
//           DIN   DOUT  KC  NKY GX PNK VEC FINAL  WOFF    PBOFF FBOFF SB
using L0A = LP<1862,  512, 133, 14, 1,  0, 4, false,       0,    0,    0,  0>;
using L0B = LP<1862,  512, 133, 14, 1,  0, 4, false,       0,    0,    0, 32>;
using L1A = LP< 512,  256, 128,  4, 1, 14, 2, false,  953344,    0,    0,  0>;
using L1B = LP< 512,  256, 128,  4, 1, 14, 2, false,  953344,    0,    0, 32>;
using L2A = LP< 256,  128,  64,  4, 1,  4, 2, false, 1084416,  512,    0,  0>;
using L2B = LP< 256,  128,  64,  4, 1,  4, 2, false, 1084416,  512,    0, 32>;
using L3A = LP< 128,  256,  32,  4, 1,  4, 2, false, 1117184,  768,    0,  0>;
using L3B = LP< 128,  256,  32,  4, 1,  4, 2, false, 1117184,  768,    0, 32>;
using L4A = LP< 256,  512,  64,  4, 2,  4, 2, false, 1149952,  896,    0,  0>;
using L4B = LP< 256,  512,  64,  4, 2,  4, 2, false, 1149952,  896,    0, 32>;
using L5A = LP< 512, 1862, 512,  1, 8,  4, 2, true,  1281024, 1152, 1664,  0>;
using L5B = LP< 512, 1862, 512,  1, 8,  4, 2, true,  1281024, 1152, 1664, 32>;

extern "C" void kernel_launch(void* const* d_in, const int* in_sizes, int n_in,
                              void* d_out, int out_size, void* d_ws, size_t ws_size,
                              hipStream_t stream)
{
    const float* x    = (const float*)d_in[0];   // [64][1862]
    const float* wts  = (const float*)d_in[1];   // [64][W_TOTAL]
    const float* bias = (const float*)d_in[2];   // [64][B_TOTAL]
    float* out = (float*)d_out;                  // [64][1862]

    // partials (floats); each slot written before read within one call
    float* p0 = (float*)d_ws;        // 14*64*512 = 458752
    float* p1 = p0 + 458752;         //  4*64*256 =  65536
    float* p2 = p1 + 65536;          //  4*64*128 =  32768
    float* p3 = p2 + 32768;          //  4*64*256 =  65536
    float* p4 = p3 + 65536;          //  4*64*512 = 131072   (~3.0 MB total)

    // Software pipeline over two sample groups — middles hide under the
    // 122 MB streaming dispatches; 7 dispatches total.
    // D1: L0(A)                                   448 blocks
    mono_kernel<L0A><<<dim3(L0A::NBLK), 128, 0, stream>>>(x, p0, wts, bias);
    // D2: L0(B) + L1(A)                           448+128 = 576
    dual_kernel<L0B, L1A><<<dim3(L0B::NBLK + L1A::NBLK), 128, 0, stream>>>(
        x, p0, p0, p1, wts, bias);
    // D3: L1(B) + L2(A)                           128+128 = 256
    dual_kernel<L1B, L2A><<<dim3(L1B::NBLK + L2A::NBLK), 128, 0, stream>>>(
        p0, p1, p1, p2, wts, bias);
    // D4: L2(B) + L3(A)                           128+128 = 256
    dual_kernel<L2B, L3A><<<dim3(L2B::NBLK + L3A::NBLK), 128, 0, stream>>>(
        p1, p2, p2, p3, wts, bias);
    // D5: L3(B) + L4(A)                           128+256 = 384
    dual_kernel<L3B, L4A><<<dim3(L3B::NBLK + L4A::NBLK), 128, 0, stream>>>(
        p2, p3, p3, p4, wts, bias);
    // D6: L4(B) + L5(A)                           256+256 = 512
    dual_kernel<L4B, L5A><<<dim3(L4B::NBLK + L5A::NBLK), 128, 0, stream>>>(
        p3, p4, p4, out, wts, bias);
    // D7: L5(B)                                   256
    mono_kernel<L5B><<<dim3(L5B::NBLK), 128, 0, stream>>>(p4, out, wts, bias);
}